// Round 1
// 319.009 us; speedup vs baseline: 1.0255x; 1.0255x over previous
//
#include <hip/hip_runtime.h>
#include <hip/hip_bf16.h>
#include <math.h>

#define N_NODES 10000
#define N_EDGES 640000
#define C 128
#define BF 16

__device__ __forceinline__ float2 bf2_to_f2(unsigned u) {
    union { unsigned x; float f; } lo, hi;
    lo.x = (u & 0xffffu) << 16;
    hi.x = u & 0xffff0000u;
    float2 r; r.x = lo.f; r.y = hi.f; return r;
}

// tanh-approx GELU: z*sigmoid(1.5957691*(z+0.044715 z^3)), exp2 domain.
// |err vs exact-erf gelu| <= ~4e-4; branchless, saturates correctly at +/-inf.
__device__ __forceinline__ float fast_gelu(float z) {
    float z2 = z * z;
    float p  = z * fmaf(0.044715f, z2, 1.0f);
    float e  = __builtin_amdgcn_exp2f(-2.3022082f * p);   // exp2(-2*0.79788456*log2e * p)
    float r  = __builtin_amdgcn_rcpf(1.0f + e);
    return z * r;
}

// --- K0: convert x to bf16 (2.56 MB -> L2-resident) ---
__global__ __launch_bounds__(256) void k_cvt(const float* __restrict__ x,
                                             __hip_bfloat16* __restrict__ xb) {
    int i = (blockIdx.x * 256 + threadIdx.x) * 4;
    float4 v = *(const float4*)(x + i);
    xb[i + 0] = __float2bfloat16(v.x);
    xb[i + 1] = __float2bfloat16(v.y);
    xb[i + 2] = __float2bfloat16(v.z);
    xb[i + 3] = __float2bfloat16(v.w);
}

// --- K1: degree counts ---
__global__ void k_deg(const int* __restrict__ ei, int* __restrict__ dr, int* __restrict__ dc) {
    int e = blockIdx.x * blockDim.x + threadIdx.x;
    if (e < N_EDGES) {
        atomicAdd(&dr[ei[e]], 1);
        atomicAdd(&dc[ei[N_EDGES + e]], 1);
    }
}

// --- K2: exclusive scan of dc -> off, plus inv-sqrt degrees ---
__global__ __launch_bounds__(1024) void k_scan(
    const int* __restrict__ dr, const int* __restrict__ dc,
    int* __restrict__ off, float* __restrict__ ir, float* __restrict__ ic)
{
    __shared__ int shp[1024];
    int t = threadIdx.x;
    int base = t * 10;
    int loc[10];
    int s = 0;
#pragma unroll
    for (int j = 0; j < 10; j++) {
        int i = base + j;
        int v = (i < N_NODES) ? dc[i] : 0;
        loc[j] = s;
        s += v;
    }
    shp[t] = s;
    __syncthreads();
    for (int st = 1; st < 1024; st <<= 1) {
        int a = (t >= st) ? shp[t - st] : 0;
        __syncthreads();
        shp[t] += a;
        __syncthreads();
    }
    int excl = shp[t] - s;
#pragma unroll
    for (int j = 0; j < 10; j++) {
        int i = base + j;
        if (i < N_NODES) {
            off[i] = excl + loc[j];
            ir[i] = rsqrtf((float)(dr[i] + 1));
            ic[i] = rsqrtf((float)(dc[i] + 1));
        }
    }
    if (t == 1023) off[N_NODES] = shp[1023];
}

// --- K3: bucket edges by destination. PACKED: store (e, r, ir[r]*ew[e]) as int4
//     so the node kernel's inner loop has a 1-level load chain. ---
template <bool PACKED>
__global__ void k_prep(const int* __restrict__ ei, const float* __restrict__ ew,
                       const float* __restrict__ ir,
                       const int* __restrict__ off, int* __restrict__ cur,
                       int4* __restrict__ bs, int* __restrict__ bucket) {
    int e = blockIdx.x * blockDim.x + threadIdx.x;
    if (e < N_EDGES) {
        int c = ei[N_EDGES + e];
        int pos = atomicAdd(&cur[c], 1);
        int slot = off[c] + pos;
        if (PACKED) {
            int r = ei[e];
            int4 v;
            v.x = e;
            v.y = r;
            v.z = __float_as_int(ir[r] * ew[e]);
            v.w = 0;
            bs[slot] = v;
        } else {
            bucket[slot] = e;
        }
    }
}

// --- K4: fused node-centric message + sum + GEMV kernel.
//     8 waves/block, one edge in flight per wave, 2 channels per lane.
//     Edge id is wave-uniform (readfirstlane) -> ea row goes through the
//     scalar (SMEM) pipe; messages accumulate in fp32 registers (no msg
//     buffer round-trip). ---
template <bool USEBF, bool PACKED>
__global__ __launch_bounds__(512) void k_node(
    const float* __restrict__ x, const __hip_bfloat16* __restrict__ xb,
    const float* __restrict__ ea, const float* __restrict__ ew,
    const float* __restrict__ Wb, const float* __restrict__ bb,
    const int* __restrict__ ei,
    const float* __restrict__ ir, const float* __restrict__ ic,
    const int* __restrict__ off, const int4* __restrict__ bs,
    const int* __restrict__ bucket,
    const float* __restrict__ Wl, const float* __restrict__ bl,
    float* __restrict__ out)
{
    int n = blockIdx.x;
    int t = threadIdx.x;
    int w = t >> 6;          // wave id 0..7 (one edge in flight per wave)
    int p = t & 63;          // channel pair: channels 2p, 2p+1
    float icn = ic[n];

    // per-lane W_bond columns for its two channels (32 VGPRs, hoisted)
    float wb0[BF], wb1[BF];
#pragma unroll
    for (int k = 0; k < BF; k++) {
        wb0[k] = Wb[(size_t)k * C + 2 * p];
        wb1[k] = Wb[(size_t)k * C + 2 * p + 1];
    }
    float bb0 = bb[2 * p], bb1 = bb[2 * p + 1];

    float a0 = 0.f, a1 = 0.f;
    int o0 = off[n], o1 = off[n + 1];

    int i = o0 + w;
    int4 cv;
    int bcur = 0;
    if (PACKED) { if (i < o1) cv = bs[i]; }
    else        { if (i < o1) bcur = bucket[i]; }

    while (i < o1) {
        int e, r; float s;
        if (PACKED) {
            e = __builtin_amdgcn_readfirstlane(cv.x);
            r = __builtin_amdgcn_readfirstlane(cv.y);
            s = __uint_as_float((unsigned)__builtin_amdgcn_readfirstlane(cv.z)) * icn;
        } else {
            e = __builtin_amdgcn_readfirstlane(bcur);
            r = ei[e];
            s = ir[r] * ew[e] * icn;
        }
        int inext = i + 8;
        if (inext < o1) {                         // prefetch next bucket entry
            if (PACKED) cv = bs[inext];
            else        bcur = bucket[inext];
        }

        // edge_attr row: e is in SGPR -> scalar loads, off the vector pipes
        const float* eap = ea + (size_t)e * BF;
        float emb0 = bb0, emb1 = bb1;
#pragma unroll
        for (int k = 0; k < BF; k++) {
            float q = eap[k];
            emb0 = fmaf(q, wb0[k], emb0);
            emb1 = fmaf(q, wb1[k], emb1);
        }

        float xr0, xr1;
        if (USEBF) {
            unsigned xu = *((const unsigned*)xb + (size_t)r * (C / 2) + p);
            float2 xf = bf2_to_f2(xu);
            xr0 = xf.x; xr1 = xf.y;
        } else {
            float2 xf = *(const float2*)(x + (size_t)r * C + 2 * p);
            xr0 = xf.x; xr1 = xf.y;
        }
        a0 = fmaf(fast_gelu(xr0 + emb0), s, a0);
        a1 = fmaf(fast_gelu(xr1 + emb1), s, a1);
        i = inext;
    }

    __shared__ float2 shp[8][64];
    __shared__ __align__(16) float shs[C];
    __shared__ float sho[4][C];

    shp[w][p] = make_float2(a0, a1);
    __syncthreads();
    if (t < 64) {
        float vx = 0.f, vy = 0.f;
#pragma unroll
        for (int k = 0; k < 8; k++) { vx += shp[k][t].x; vy += shp[k][t].y; }
        float sl = ir[n] * icn;                  // self-loop norm
        float x0, x1;
        if (USEBF) {
            float2 xf = bf2_to_f2(*((const unsigned*)xb + (size_t)n * (C / 2) + t));
            x0 = xf.x; x1 = xf.y;
        } else {
            float2 xf = *(const float2*)(x + (size_t)n * C + 2 * t);
            x0 = xf.x; x1 = xf.y;
        }
        shs[2 * t]     = vx + fast_gelu(x0) * sl;
        shs[2 * t + 1] = vy + fast_gelu(x1) * sl;
    }
    __syncthreads();

    // GEMV epilogue: quarter = k-range [32*q, 32*q+32), ch = output channel
    int ch = t & (C - 1), q = t >> 7;
    float o = 0.f;
    const float4* shv = (const float4*)shs + q * 8;
    const float* wcol = Wl + (size_t)(q * 32) * C + ch;
#pragma unroll
    for (int k4 = 0; k4 < 8; k4++) {
        float4 sv = shv[k4];                     // LDS broadcast
        o = fmaf(sv.x, wcol[(size_t)(k4 * 4 + 0) * C], o);
        o = fmaf(sv.y, wcol[(size_t)(k4 * 4 + 1) * C], o);
        o = fmaf(sv.z, wcol[(size_t)(k4 * 4 + 2) * C], o);
        o = fmaf(sv.w, wcol[(size_t)(k4 * 4 + 3) * C], o);
    }
    sho[q][ch] = o;
    __syncthreads();
    if (t < C) out[(size_t)n * C + t] = bl[t] + sho[0][t] + sho[1][t] + sho[2][t] + sho[3][t];
}

extern "C" void kernel_launch(void* const* d_in, const int* in_sizes, int n_in,
                              void* d_out, int out_size, void* d_ws, size_t ws_size,
                              hipStream_t stream) {
    const float* x  = (const float*)d_in[0];
    const float* ea = (const float*)d_in[1];
    const float* ew = (const float*)d_in[2];
    const float* Wb = (const float*)d_in[3];
    const float* bb = (const float*)d_in[4];
    const float* Wl = (const float*)d_in[5];
    const float* bl = (const float*)d_in[6];
    const int*   ei = (const int*)d_in[7];
    float* out = (float*)d_out;

    const size_t small_ints = (size_t)(10304 + 5 * 10240) * 4;      // off,dr,dc,cur,ir,ic
    const size_t need_A = (size_t)640000 * 16 + (size_t)640000 * 4 + small_ints; // bs+xb
    const size_t need_B = (size_t)640000 * 16 + small_ints;                      // bs only
    const size_t need_C = (size_t)640000 * 4 + small_ints;                       // bucket only

    if (ws_size >= need_B) {
        bool usebf = ws_size >= need_A;
        int4* bs = (int4*)d_ws;
        unsigned* xbu = (unsigned*)(bs + 640000);
        int* off = (int*)(xbu + (usebf ? 640000 : 0));
        int* dr  = off + 10304;
        int* dc  = dr + 10240;
        int* cur = dc + 10240;
        float* ir = (float*)(cur + 10240);
        float* ic = ir + 10240;
        __hip_bfloat16* xb = (__hip_bfloat16*)xbu;

        hipMemsetAsync(dr, 0, 3 * 10240 * sizeof(int), stream);     // dr, dc, cur
        if (usebf) k_cvt<<<1250, 256, 0, stream>>>(x, xb);
        k_deg<<<(N_EDGES + 255) / 256, 256, 0, stream>>>(ei, dr, dc);
        k_scan<<<1, 1024, 0, stream>>>(dr, dc, off, ir, ic);
        k_prep<true><<<(N_EDGES + 255) / 256, 256, 0, stream>>>(ei, ew, ir, off, cur, bs, nullptr);
        if (usebf)
            k_node<true, true><<<N_NODES, 512, 0, stream>>>(
                x, xb, ea, ew, Wb, bb, ei, ir, ic, off, bs, nullptr, Wl, bl, out);
        else
            k_node<false, true><<<N_NODES, 512, 0, stream>>>(
                x, nullptr, ea, ew, Wb, bb, ei, ir, ic, off, bs, nullptr, Wl, bl, out);
    } else {
        // minimal-workspace fallback: int bucket + fp32 x
        int* bucket = (int*)d_ws;
        int* off = bucket + 640000;
        int* dr  = off + 10304;
        int* dc  = dr + 10240;
        int* cur = dc + 10240;
        float* ir = (float*)(cur + 10240);
        float* ic = ir + 10240;
        (void)need_C;

        hipMemsetAsync(dr, 0, 3 * 10240 * sizeof(int), stream);
        k_deg<<<(N_EDGES + 255) / 256, 256, 0, stream>>>(ei, dr, dc);
        k_scan<<<1, 1024, 0, stream>>>(dr, dc, off, ir, ic);
        k_prep<false><<<(N_EDGES + 255) / 256, 256, 0, stream>>>(ei, ew, ir, off, cur, nullptr, bucket);
        k_node<false, false><<<N_NODES, 512, 0, stream>>>(
            x, nullptr, ea, ew, Wb, bb, ei, ir, ic, off, nullptr, bucket, Wl, bl, out);
    }
}

// Round 4
// 305.186 us; speedup vs baseline: 1.0720x; 1.0453x over previous
//
#include <hip/hip_runtime.h>
#include <hip/hip_bf16.h>
#include <math.h>

#define N_NODES 10000
#define N_EDGES 640000
#define C 128
#define BF 16

typedef int iv4 __attribute__((ext_vector_type(4)));   // NT-load-compatible int4

__device__ __forceinline__ float2 bf2_to_f2(unsigned u) {
    union { unsigned x; float f; } lo, hi;
    lo.x = (u & 0xffffu) << 16;
    hi.x = u & 0xffff0000u;
    float2 r; r.x = lo.f; r.y = hi.f; return r;
}

// tanh-approx GELU: z*sigmoid(1.5957691*(z+0.044715 z^3)), exp2 domain.
// |err vs exact-erf gelu| <= ~4e-4; branchless, saturates correctly at +/-inf.
__device__ __forceinline__ float fast_gelu(float z) {
    float z2 = z * z;
    float p  = z * fmaf(0.044715f, z2, 1.0f);
    float e  = __builtin_amdgcn_exp2f(-2.3022082f * p);   // exp2(-2*0.79788456*log2e * p)
    float r  = __builtin_amdgcn_rcpf(1.0f + e);
    return z * r;
}

// --- K0 (full path): fused x->bf16 convert + degree count + slot position.
//     pos[e] = atomicAdd(dc[c]) return value IS the within-node slot, making
//     the later bucket-build atomic-free. ---
__global__ __launch_bounds__(256) void k_pre(
    const float* __restrict__ x, __hip_bfloat16* __restrict__ xb,
    const int* __restrict__ ei, int* __restrict__ dr, int* __restrict__ dc,
    int* __restrict__ pos)
{
    int b = blockIdx.x;
    if (b < 1250) {
        int i = (b * 256 + threadIdx.x) * 4;
        float4 v = *(const float4*)(x + i);
        xb[i + 0] = __float2bfloat16(v.x);
        xb[i + 1] = __float2bfloat16(v.y);
        xb[i + 2] = __float2bfloat16(v.z);
        xb[i + 3] = __float2bfloat16(v.w);
    } else {
        int e = (b - 1250) * 256 + threadIdx.x;   // 2500*256 == N_EDGES exactly
        int r = ei[e];
        int c = ei[N_EDGES + e];
        atomicAdd(&dr[r], 1);
        pos[e] = atomicAdd(&dc[c], 1);
    }
}

// --- K1 (fallback): degree counts only ---
__global__ void k_deg(const int* __restrict__ ei, int* __restrict__ dr, int* __restrict__ dc) {
    int e = blockIdx.x * blockDim.x + threadIdx.x;
    if (e < N_EDGES) {
        atomicAdd(&dr[ei[e]], 1);
        atomicAdd(&dc[ei[N_EDGES + e]], 1);
    }
}

// --- K2: exclusive scan of dc -> off, plus inv-sqrt degrees ---
__global__ __launch_bounds__(1024) void k_scan(
    const int* __restrict__ dr, const int* __restrict__ dc,
    int* __restrict__ off, float* __restrict__ ir, float* __restrict__ ic)
{
    __shared__ int shp[1024];
    int t = threadIdx.x;
    int base = t * 10;
    int loc[10];
    int s = 0;
#pragma unroll
    for (int j = 0; j < 10; j++) {
        int i = base + j;
        int v = (i < N_NODES) ? dc[i] : 0;
        loc[j] = s;
        s += v;
    }
    shp[t] = s;
    __syncthreads();
    for (int st = 1; st < 1024; st <<= 1) {
        int a = (t >= st) ? shp[t - st] : 0;
        __syncthreads();
        shp[t] += a;
        __syncthreads();
    }
    int excl = shp[t] - s;
#pragma unroll
    for (int j = 0; j < 10; j++) {
        int i = base + j;
        if (i < N_NODES) {
            off[i] = excl + loc[j];
            ir[i] = rsqrtf((float)(dr[i] + 1));
            ic[i] = rsqrtf((float)(dc[i] + 1));
        }
    }
    if (t == 1023) off[N_NODES] = shp[1023];
}

// --- K3 (full path): atomic-free bucket build. slot = off[c] + pos[e].
//     Packed (e, r, ir[r]*ew[e]) so k_node's load chain is 1 level. ---
__global__ __launch_bounds__(256) void k_prep2(
    const int* __restrict__ ei, const float* __restrict__ ew,
    const float* __restrict__ ir, const int* __restrict__ off,
    const int* __restrict__ pos, iv4* __restrict__ bs)
{
    int e = blockIdx.x * 256 + threadIdx.x;
    int r = ei[e];
    int c = ei[N_EDGES + e];
    iv4 v;
    v.x = e;
    v.y = r;
    v.z = __float_as_int(ir[r] * ew[e]);
    v.w = 0;
    bs[off[c] + pos[e]] = v;
}

// --- K3 (fallback): bucket with atomics ---
__global__ void k_scatter(const int* __restrict__ ei, const int* __restrict__ off,
                          int* __restrict__ cur, int* __restrict__ bucket) {
    int e = blockIdx.x * blockDim.x + threadIdx.x;
    if (e < N_EDGES) {
        int c = ei[N_EDGES + e];
        int pos = atomicAdd(&cur[c], 1);
        bucket[off[c] + pos] = e;
    }
}

// --- K4: fused node kernel, 2 edges in flight per wave.
//     8 waves/block, wave w owns entries o0+w, o0+w+8, ... ; each iteration
//     processes (i, i+8) with all operand loads (bucket-prefetched entries,
//     scalar ea rows, x gathers) issued before any use -> latency amortized
//     over 2 edges' VALU work. Accumulation order identical to 1-edge loop. ---
template <bool USEBF>
__global__ __launch_bounds__(512) void k_node(
    const float* __restrict__ x, const __hip_bfloat16* __restrict__ xb,
    const float* __restrict__ ea,
    const float* __restrict__ Wb, const float* __restrict__ bb,
    const float* __restrict__ ir, const float* __restrict__ ic,
    const int* __restrict__ off, const iv4* __restrict__ bs,
    const float* __restrict__ Wl, const float* __restrict__ bl,
    float* __restrict__ out)
{
    int n = blockIdx.x;
    int t = threadIdx.x;
    int w = t >> 6;          // wave id 0..7
    int p = t & 63;          // channel pair: channels 2p, 2p+1
    float icn = ic[n];

    // per-lane W_bond columns for its two channels (hoisted)
    float2 wb[BF];
#pragma unroll
    for (int k = 0; k < BF; k++)
        wb[k] = *(const float2*)(Wb + (size_t)k * C + 2 * p);
    float2 bbv = *(const float2*)(bb + 2 * p);

    float a0 = 0.f, a1 = 0.f;
    int o0 = off[n], o1 = off[n + 1];
    const unsigned* xbu = (const unsigned*)xb;

    int i = o0 + w;
    bool hA = (i < o1), hB = (i + 8 < o1);
    iv4 vA, vB;
    vA.x = 0; vA.y = 0; vA.z = 0; vA.w = 0;
    if (hA) vA = __builtin_nontemporal_load(bs + i);
    vB = vA;
    if (hB) vB = __builtin_nontemporal_load(bs + i + 8);

    while (hA) {
        int eA = __builtin_amdgcn_readfirstlane(vA.x);
        int rA = __builtin_amdgcn_readfirstlane(vA.y);
        float sA = __uint_as_float((unsigned)__builtin_amdgcn_readfirstlane(vA.z)) * icn;
        int eB = __builtin_amdgcn_readfirstlane(vB.x);
        int rB = __builtin_amdgcn_readfirstlane(vB.y);
        float sB = hB ? __uint_as_float((unsigned)__builtin_amdgcn_readfirstlane(vB.z)) * icn
                      : 0.0f;

        // prefetch next pair of bucket entries
        int i2 = i + 16;
        bool hA2 = (i2 < o1), hB2 = (i2 + 8 < o1);
        iv4 vA2 = vA, vB2 = vA;
        if (hA2) vA2 = __builtin_nontemporal_load(bs + i2);
        vB2 = vA2;
        if (hB2) vB2 = __builtin_nontemporal_load(bs + i2 + 8);

        // issue both edges' operand loads (eA/eB uniform -> scalar pipe)
        const float4* eapA = (const float4*)(ea + (size_t)eA * BF);
        const float4* eapB = (const float4*)(ea + (size_t)eB * BF);
        float4 qA0 = eapA[0], qA1 = eapA[1], qA2 = eapA[2], qA3 = eapA[3];
        float4 qB0 = eapB[0], qB1 = eapB[1], qB2 = eapB[2], qB3 = eapB[3];
        float xA0, xA1, xB0, xB1;
        if (USEBF) {
            unsigned xuA = xbu[(size_t)rA * 64 + p];
            unsigned xuB = xbu[(size_t)rB * 64 + p];
            float2 fA = bf2_to_f2(xuA);
            float2 fB = bf2_to_f2(xuB);
            xA0 = fA.x; xA1 = fA.y; xB0 = fB.x; xB1 = fB.y;
        } else {
            float2 fA = *(const float2*)(x + (size_t)rA * C + 2 * p);
            float2 fB = *(const float2*)(x + (size_t)rB * C + 2 * p);
            xA0 = fA.x; xA1 = fA.y; xB0 = fB.x; xB1 = fB.y;
        }

        // edge A
        float m0 = bbv.x, m1 = bbv.y;
        m0 = fmaf(qA0.x, wb[0].x, m0);   m1 = fmaf(qA0.x, wb[0].y, m1);
        m0 = fmaf(qA0.y, wb[1].x, m0);   m1 = fmaf(qA0.y, wb[1].y, m1);
        m0 = fmaf(qA0.z, wb[2].x, m0);   m1 = fmaf(qA0.z, wb[2].y, m1);
        m0 = fmaf(qA0.w, wb[3].x, m0);   m1 = fmaf(qA0.w, wb[3].y, m1);
        m0 = fmaf(qA1.x, wb[4].x, m0);   m1 = fmaf(qA1.x, wb[4].y, m1);
        m0 = fmaf(qA1.y, wb[5].x, m0);   m1 = fmaf(qA1.y, wb[5].y, m1);
        m0 = fmaf(qA1.z, wb[6].x, m0);   m1 = fmaf(qA1.z, wb[6].y, m1);
        m0 = fmaf(qA1.w, wb[7].x, m0);   m1 = fmaf(qA1.w, wb[7].y, m1);
        m0 = fmaf(qA2.x, wb[8].x, m0);   m1 = fmaf(qA2.x, wb[8].y, m1);
        m0 = fmaf(qA2.y, wb[9].x, m0);   m1 = fmaf(qA2.y, wb[9].y, m1);
        m0 = fmaf(qA2.z, wb[10].x, m0);  m1 = fmaf(qA2.z, wb[10].y, m1);
        m0 = fmaf(qA2.w, wb[11].x, m0);  m1 = fmaf(qA2.w, wb[11].y, m1);
        m0 = fmaf(qA3.x, wb[12].x, m0);  m1 = fmaf(qA3.x, wb[12].y, m1);
        m0 = fmaf(qA3.y, wb[13].x, m0);  m1 = fmaf(qA3.y, wb[13].y, m1);
        m0 = fmaf(qA3.z, wb[14].x, m0);  m1 = fmaf(qA3.z, wb[14].y, m1);
        m0 = fmaf(qA3.w, wb[15].x, m0);  m1 = fmaf(qA3.w, wb[15].y, m1);
        a0 = fmaf(fast_gelu(xA0 + m0), sA, a0);
        a1 = fmaf(fast_gelu(xA1 + m1), sA, a1);

        // edge B (sB==0 when absent; loads aliased to A's rows, so safe)
        float n0 = bbv.x, n1 = bbv.y;
        n0 = fmaf(qB0.x, wb[0].x, n0);   n1 = fmaf(qB0.x, wb[0].y, n1);
        n0 = fmaf(qB0.y, wb[1].x, n0);   n1 = fmaf(qB0.y, wb[1].y, n1);
        n0 = fmaf(qB0.z, wb[2].x, n0);   n1 = fmaf(qB0.z, wb[2].y, n1);
        n0 = fmaf(qB0.w, wb[3].x, n0);   n1 = fmaf(qB0.w, wb[3].y, n1);
        n0 = fmaf(qB1.x, wb[4].x, n0);   n1 = fmaf(qB1.x, wb[4].y, n1);
        n0 = fmaf(qB1.y, wb[5].x, n0);   n1 = fmaf(qB1.y, wb[5].y, n1);
        n0 = fmaf(qB1.z, wb[6].x, n0);   n1 = fmaf(qB1.z, wb[6].y, n1);
        n0 = fmaf(qB1.w, wb[7].x, n0);   n1 = fmaf(qB1.w, wb[7].y, n1);
        n0 = fmaf(qB2.x, wb[8].x, n0);   n1 = fmaf(qB2.x, wb[8].y, n1);
        n0 = fmaf(qB2.y, wb[9].x, n0);   n1 = fmaf(qB2.y, wb[9].y, n1);
        n0 = fmaf(qB2.z, wb[10].x, n0);  n1 = fmaf(qB2.z, wb[10].y, n1);
        n0 = fmaf(qB2.w, wb[11].x, n0);  n1 = fmaf(qB2.w, wb[11].y, n1);
        n0 = fmaf(qB3.x, wb[12].x, n0);  n1 = fmaf(qB3.x, wb[12].y, n1);
        n0 = fmaf(qB3.y, wb[13].x, n0);  n1 = fmaf(qB3.y, wb[13].y, n1);
        n0 = fmaf(qB3.z, wb[14].x, n0);  n1 = fmaf(qB3.z, wb[14].y, n1);
        n0 = fmaf(qB3.w, wb[15].x, n0);  n1 = fmaf(qB3.w, wb[15].y, n1);
        a0 = fmaf(fast_gelu(xB0 + n0), sB, a0);
        a1 = fmaf(fast_gelu(xB1 + n1), sB, a1);

        vA = vA2; vB = vB2; hA = hA2; hB = hB2; i = i2;
    }

    __shared__ float2 shp[8][64];
    __shared__ __align__(16) float shs[C];
    __shared__ float sho[4][C];

    shp[w][p] = make_float2(a0, a1);
    __syncthreads();
    if (t < 64) {
        float vx = 0.f, vy = 0.f;
#pragma unroll
        for (int k = 0; k < 8; k++) { vx += shp[k][t].x; vy += shp[k][t].y; }
        float sl = ir[n] * icn;                  // self-loop norm
        float x0, x1;
        if (USEBF) {
            float2 xf = bf2_to_f2(*((const unsigned*)xb + (size_t)n * (C / 2) + t));
            x0 = xf.x; x1 = xf.y;
        } else {
            float2 xf = *(const float2*)(x + (size_t)n * C + 2 * t);
            x0 = xf.x; x1 = xf.y;
        }
        shs[2 * t]     = vx + fast_gelu(x0) * sl;
        shs[2 * t + 1] = vy + fast_gelu(x1) * sl;
    }
    __syncthreads();

    // GEMV epilogue: quarter = k-range [32*q, 32*q+32), ch = output channel
    int ch = t & (C - 1), q = t >> 7;
    float o = 0.f;
    const float4* shv = (const float4*)shs + q * 8;
    const float* wcol = Wl + (size_t)(q * 32) * C + ch;
#pragma unroll
    for (int k4 = 0; k4 < 8; k4++) {
        float4 sv = shv[k4];                     // LDS broadcast
        o = fmaf(sv.x, wcol[(size_t)(k4 * 4 + 0) * C], o);
        o = fmaf(sv.y, wcol[(size_t)(k4 * 4 + 1) * C], o);
        o = fmaf(sv.z, wcol[(size_t)(k4 * 4 + 2) * C], o);
        o = fmaf(sv.w, wcol[(size_t)(k4 * 4 + 3) * C], o);
    }
    sho[q][ch] = o;
    __syncthreads();
    if (t < C) out[(size_t)n * C + t] = bl[t] + sho[0][t] + sho[1][t] + sho[2][t] + sho[3][t];
}

// --- fallback node kernel (minimal workspace): gather via int bucket ---
__global__ __launch_bounds__(512) void k_node_fb(
    const float* __restrict__ x,
    const float* __restrict__ ea, const float* __restrict__ ew,
    const float* __restrict__ Wb, const float* __restrict__ bb,
    const int* __restrict__ ei,
    const float* __restrict__ ir, const float* __restrict__ ic,
    const int* __restrict__ off, const int* __restrict__ bucket,
    const float* __restrict__ Wl, const float* __restrict__ bl,
    float* __restrict__ out)
{
    int n = blockIdx.x;
    int t = threadIdx.x & (C - 1);
    int g = threadIdx.x >> 7;
    float icn = ic[n];
    float wb[BF];
#pragma unroll
    for (int k = 0; k < BF; k++) wb[k] = Wb[(size_t)k * C + t];
    float bbt = bb[t];
    float acc = 0.0f;
    if (g == 0) acc = fast_gelu(x[(size_t)n * C + t]) * (ir[n] * icn);
    int o0 = off[n], o1 = off[n + 1];
    for (int i = o0 + g; i < o1; i += 4) {
        int e = __builtin_amdgcn_readfirstlane(bucket[i]);
        int r = ei[e];
        float s = ir[r] * icn * ew[e];
        const float4* eapt = (const float4*)(ea + (size_t)e * BF);
        float4 q0 = eapt[0], q1 = eapt[1], q2 = eapt[2], q3 = eapt[3];
        float emb = bbt;
        emb = fmaf(q0.x, wb[0], emb);  emb = fmaf(q0.y, wb[1], emb);
        emb = fmaf(q0.z, wb[2], emb);  emb = fmaf(q0.w, wb[3], emb);
        emb = fmaf(q1.x, wb[4], emb);  emb = fmaf(q1.y, wb[5], emb);
        emb = fmaf(q1.z, wb[6], emb);  emb = fmaf(q1.w, wb[7], emb);
        emb = fmaf(q2.x, wb[8], emb);  emb = fmaf(q2.y, wb[9], emb);
        emb = fmaf(q2.z, wb[10], emb); emb = fmaf(q2.w, wb[11], emb);
        emb = fmaf(q3.x, wb[12], emb); emb = fmaf(q3.y, wb[13], emb);
        emb = fmaf(q3.z, wb[14], emb); emb = fmaf(q3.w, wb[15], emb);
        acc = fmaf(fast_gelu(x[(size_t)r * C + t] + emb), s, acc);
    }
    __shared__ float shp[4][C];
    __shared__ float shs[C];
    shp[g][t] = acc;
    __syncthreads();
    if (threadIdx.x < C) {
        int k = threadIdx.x;
        shs[k] = shp[0][k] + shp[1][k] + shp[2][k] + shp[3][k];
    }
    __syncthreads();
    float o = 0.0f;
    int k0 = g * 32;
#pragma unroll 8
    for (int j = 0; j < 32; j++) {
        int k = k0 + j;
        o = fmaf(shs[k], Wl[(size_t)k * C + t], o);
    }
    shp[g][t] = o;
    __syncthreads();
    if (threadIdx.x < C) {
        int c = threadIdx.x;
        out[(size_t)n * C + c] = bl[c] + shp[0][c] + shp[1][c] + shp[2][c] + shp[3][c];
    }
}

extern "C" void kernel_launch(void* const* d_in, const int* in_sizes, int n_in,
                              void* d_out, int out_size, void* d_ws, size_t ws_size,
                              hipStream_t stream) {
    const float* x  = (const float*)d_in[0];
    const float* ea = (const float*)d_in[1];
    const float* ew = (const float*)d_in[2];
    const float* Wb = (const float*)d_in[3];
    const float* bb = (const float*)d_in[4];
    const float* Wl = (const float*)d_in[5];
    const float* bl = (const float*)d_in[6];
    const int*   ei = (const int*)d_in[7];
    float* out = (float*)d_out;

    // full path: bs (10.24MB) + xb (2.56MB) + pos (2.56MB) + small arrays
    const size_t need_full = (size_t)640000 * 16 + (size_t)640000 * 4
                           + (size_t)640000 * 4
                           + (size_t)(10304 + 4 * 10240) * 4;

    if (ws_size >= need_full) {
        iv4* bs = (iv4*)d_ws;
        unsigned* xbu = (unsigned*)(bs + 640000);           // 640000 u32 = xb bf16 pairs
        int* pos = (int*)(xbu + 640000);
        int* off = pos + 640000;
        int* dr  = off + 10304;
        int* dc  = dr + 10240;
        float* ir = (float*)(dc + 10240);
        float* ic = ir + 10240;
        __hip_bfloat16* xb = (__hip_bfloat16*)xbu;

        (void)hipMemsetAsync(dr, 0, 2 * 10240 * sizeof(int), stream);   // dr, dc
        k_pre<<<3750, 256, 0, stream>>>(x, xb, ei, dr, dc, pos);
        k_scan<<<1, 1024, 0, stream>>>(dr, dc, off, ir, ic);
        k_prep2<<<2500, 256, 0, stream>>>(ei, ew, ir, off, pos, bs);
        k_node<true><<<N_NODES, 512, 0, stream>>>(
            x, xb, ea, Wb, bb, ir, ic, off, bs, Wl, bl, out);
    } else {
        // minimal-workspace fallback: int bucket + fp32 x
        int* bucket = (int*)d_ws;
        int* off = bucket + 640000;
        int* dr  = off + 10304;
        int* dc  = dr + 10240;
        int* cur = dc + 10240;
        float* ir = (float*)(cur + 10240);
        float* ic = ir + 10240;

        (void)hipMemsetAsync(dr, 0, 3 * 10240 * sizeof(int), stream);
        k_deg<<<(N_EDGES + 255) / 256, 256, 0, stream>>>(ei, dr, dc);
        k_scan<<<1, 1024, 0, stream>>>(dr, dc, off, ir, ic);
        k_scatter<<<(N_EDGES + 255) / 256, 256, 0, stream>>>(ei, off, cur, bucket);
        k_node_fb<<<N_NODES, 512, 0, stream>>>(
            x, ea, ew, Wb, bb, ei, ir, ic, off, bucket, Wl, bl, out);
    }
}